// Round 3
// baseline (70474.854 us; speedup 1.0000x reference)
//
#include <hip/hip_runtime.h>
#include <stdint.h>
#include <math.h>

// Problem constants (fixed by setup_inputs)
#define B_     128
#define S_     128
#define V_     8000
#define E_     512
#define H_     2048
#define H4_    8192
#define GIVEN_ 64

// ---------------------------------------------------------------------------
// Threefry-2x32 (20 rounds) — exact JAX semantics
// ---------------------------------------------------------------------------
__device__ __forceinline__ uint32_t rotl32(uint32_t v, int d) {
  return (v << d) | (v >> (32 - d));
}

__device__ __forceinline__ void threefry2x32(uint32_t k0, uint32_t k1,
                                             uint32_t x0, uint32_t x1,
                                             uint32_t& o0, uint32_t& o1) {
  uint32_t k2 = k0 ^ k1 ^ 0x1BD11BDAu;
  x0 += k0; x1 += k1;
#define TF_RND(R) { x0 += x1; x1 = rotl32(x1, (R)); x1 ^= x0; }
  TF_RND(13) TF_RND(15) TF_RND(26) TF_RND(6)
  x0 += k1; x1 += k2 + 1u;
  TF_RND(17) TF_RND(29) TF_RND(16) TF_RND(24)
  x0 += k2; x1 += k0 + 2u;
  TF_RND(13) TF_RND(15) TF_RND(26) TF_RND(6)
  x0 += k0; x1 += k1 + 3u;
  TF_RND(17) TF_RND(29) TF_RND(16) TF_RND(24)
  x0 += k1; x1 += k2 + 4u;
  TF_RND(13) TF_RND(15) TF_RND(26) TF_RND(6)
  x0 += k2; x1 += k0 + 5u;
#undef TF_RND
  o0 = x0; o1 = x1;
}

// keys = jax.random.split(jax.random.key(1), 64) with jax_threefry_partitionable
// (default since JAX 0.4.36): fold-like split.
// keys[t] = threefry2x32(key=(0,1), counter=(0,t)) -> (o0, o1) stacked.
__global__ void keys_kernel(uint32_t* __restrict__ keys) {
  int t = threadIdx.x;  // 0..63
  uint32_t o0, o1;
  threefry2x32(0u, 1u, 0u, (uint32_t)t, o0, o1);
  keys[2 * t]     = o0;
  keys[2 * t + 1] = o1;
}

// out[:, :GIVEN] = x[:, :GIVEN]
__global__ void copy_prefix(const int* __restrict__ x, int* __restrict__ out) {
  int idx = blockIdx.x * blockDim.x + threadIdx.x;  // b*GIVEN + s
  int b = idx >> 6;   // /64
  int s = idx & 63;
  out[b * S_ + s] = x[b * S_ + s];
}

// ---------------------------------------------------------------------------
// Fused dual GEMM (NT): C = A1 @ W1^T  [+ A2 @ W2^T]  [+ bias]
// A row-major (M x K), W row-major (N x K). Optional row gather for A1:
// row m of A1 = A1 + ridx[m*ridx_stride]*lda1  (embedding lookup fused in).
// Tiles: BM=BN=64, BK=16, 256 threads, 4x4 microtile per thread.
// ---------------------------------------------------------------------------
__global__ __launch_bounds__(256) void gemm2_nt(
    const float* __restrict__ A1, int lda1,
    const int* __restrict__ ridx, int ridx_stride,
    const float* __restrict__ W1, int K1,
    const float* __restrict__ A2, int lda2,
    const float* __restrict__ W2, int K2,
    const float* __restrict__ bias,
    float* __restrict__ C, int ldc)
{
  __shared__ float As[16][65];
  __shared__ float Ws[16][65];
  const int m0 = blockIdx.y * 64;
  const int n0 = blockIdx.x * 64;
  const int tid = threadIdx.x;
  const int tm = tid >> 4;        // 0..15 (row group)
  const int tn = tid & 15;        // 0..15 (col group)
  const int lr = tid >> 2;        // 0..63 (load row)
  const int lc = (tid & 3) << 2;  // 0,4,8,12 (load col base)

  float acc[4][4] = {};

  // ---- phase 1: A1 @ W1^T ----
  {
    const float* arow = ridx
        ? (A1 + (size_t)ridx[(size_t)(m0 + lr) * ridx_stride] * lda1)
        : (A1 + (size_t)(m0 + lr) * lda1);
    const float* wrow = W1 + (size_t)(n0 + lr) * K1;
    for (int k0 = 0; k0 < K1; k0 += 16) {
      float4 av = *(const float4*)(arow + k0 + lc);
      float4 wv = *(const float4*)(wrow + k0 + lc);
      __syncthreads();
      As[lc + 0][lr] = av.x; As[lc + 1][lr] = av.y; As[lc + 2][lr] = av.z; As[lc + 3][lr] = av.w;
      Ws[lc + 0][lr] = wv.x; Ws[lc + 1][lr] = wv.y; Ws[lc + 2][lr] = wv.z; Ws[lc + 3][lr] = wv.w;
      __syncthreads();
#pragma unroll
      for (int kk = 0; kk < 16; ++kk) {
        float a0 = As[kk][tm * 4 + 0], a1 = As[kk][tm * 4 + 1];
        float a2 = As[kk][tm * 4 + 2], a3 = As[kk][tm * 4 + 3];
        float b0 = Ws[kk][tn * 4 + 0], b1 = Ws[kk][tn * 4 + 1];
        float b2 = Ws[kk][tn * 4 + 2], b3 = Ws[kk][tn * 4 + 3];
        acc[0][0] += a0 * b0; acc[0][1] += a0 * b1; acc[0][2] += a0 * b2; acc[0][3] += a0 * b3;
        acc[1][0] += a1 * b0; acc[1][1] += a1 * b1; acc[1][2] += a1 * b2; acc[1][3] += a1 * b3;
        acc[2][0] += a2 * b0; acc[2][1] += a2 * b1; acc[2][2] += a2 * b2; acc[2][3] += a2 * b3;
        acc[3][0] += a3 * b0; acc[3][1] += a3 * b1; acc[3][2] += a3 * b2; acc[3][3] += a3 * b3;
      }
    }
  }

  // ---- phase 2: + A2 @ W2^T (skipped when K2 == 0) ----
  if (K2 > 0) {
    const float* arow = A2 + (size_t)(m0 + lr) * lda2;
    const float* wrow = W2 + (size_t)(n0 + lr) * K2;
    for (int k0 = 0; k0 < K2; k0 += 16) {
      float4 av = *(const float4*)(arow + k0 + lc);
      float4 wv = *(const float4*)(wrow + k0 + lc);
      __syncthreads();
      As[lc + 0][lr] = av.x; As[lc + 1][lr] = av.y; As[lc + 2][lr] = av.z; As[lc + 3][lr] = av.w;
      Ws[lc + 0][lr] = wv.x; Ws[lc + 1][lr] = wv.y; Ws[lc + 2][lr] = wv.z; Ws[lc + 3][lr] = wv.w;
      __syncthreads();
#pragma unroll
      for (int kk = 0; kk < 16; ++kk) {
        float a0 = As[kk][tm * 4 + 0], a1 = As[kk][tm * 4 + 1];
        float a2 = As[kk][tm * 4 + 2], a3 = As[kk][tm * 4 + 3];
        float b0 = Ws[kk][tn * 4 + 0], b1 = Ws[kk][tn * 4 + 1];
        float b2 = Ws[kk][tn * 4 + 2], b3 = Ws[kk][tn * 4 + 3];
        acc[0][0] += a0 * b0; acc[0][1] += a0 * b1; acc[0][2] += a0 * b2; acc[0][3] += a0 * b3;
        acc[1][0] += a1 * b0; acc[1][1] += a1 * b1; acc[1][2] += a1 * b2; acc[1][3] += a1 * b3;
        acc[2][0] += a2 * b0; acc[2][1] += a2 * b1; acc[2][2] += a2 * b2; acc[2][3] += a2 * b3;
        acc[3][0] += a3 * b0; acc[3][1] += a3 * b1; acc[3][2] += a3 * b2; acc[3][3] += a3 * b3;
      }
    }
  }

  // ---- epilogue ----
#pragma unroll
  for (int i = 0; i < 4; ++i) {
    float* crow = C + (size_t)(m0 + tm * 4 + i) * ldc + n0 + tn * 4;
#pragma unroll
    for (int j = 0; j < 4; ++j) {
      float v = acc[i][j];
      if (bias) v += bias[n0 + tn * 4 + j];
      crow[j] = v;
    }
  }
}

// ---------------------------------------------------------------------------
// LSTM gate update: g is (B x 4H) pre-activation WITHOUT bias; biases added
// here. Gate order from jnp.split: i, f, g, o.
// ---------------------------------------------------------------------------
__global__ __launch_bounds__(256) void gates_kernel(
    const float* __restrict__ g, const float* __restrict__ bih,
    const float* __restrict__ bhh, float* __restrict__ h, float* __restrict__ c)
{
  int idx = blockIdx.x * blockDim.x + threadIdx.x;  // b*H + n
  int b = idx >> 11;   // / 2048
  int n = idx & (H_ - 1);
  const float* gb = g + (size_t)b * H4_;
  float gi = gb[n]           + bih[n]           + bhh[n];
  float gf = gb[n + H_]      + bih[n + H_]      + bhh[n + H_];
  float gg = gb[n + 2 * H_]  + bih[n + 2 * H_]  + bhh[n + 2 * H_];
  float go = gb[n + 3 * H_]  + bih[n + 3 * H_]  + bhh[n + 3 * H_];
  float si = 1.f / (1.f + expf(-gi));
  float sf = 1.f / (1.f + expf(-gf));
  float so = 1.f / (1.f + expf(-go));
  float cv = sf * c[idx] + si * tanhf(gg);
  c[idx] = cv;
  h[idx] = so * tanhf(cv);
}

// ---------------------------------------------------------------------------
// categorical sampling: argmax_v (logits[b][v] + gumbel[b][v]).
// jax_threefry_partitionable layout for 32-bit random bits of shape (B,V):
//   bits1, bits2 = threefry2x32(key_t, (j >> 32, j & 0xffffffff))  (j = flat idx)
//   bits[j]      = bits1 ^ bits2          <-- XOR of BOTH output lanes
// (jax/_src/prng.py::_threefry_random_bits_partitionable, bit_width==32 path.)
// One block per batch row; first-index tie-break (jnp.argmax semantics).
// ---------------------------------------------------------------------------
__global__ __launch_bounds__(256) void sample_kernel(
    const float* __restrict__ logits, const uint32_t* __restrict__ keys,
    int t, int* __restrict__ out, int col)
{
  const int b = blockIdx.x;
  const int tid = threadIdx.x;
  const uint32_t k0 = keys[2 * t];
  const uint32_t k1 = keys[2 * t + 1];
  const float* lrow = logits + (size_t)b * V_;

  float best = -3.4e38f;
  int bestIdx = 0;
  for (int v = tid; v < V_; v += 256) {
    uint32_t j = (uint32_t)(b * V_ + v);
    uint32_t o0, o1;
    threefry2x32(k0, k1, 0u, j, o0, o1);
    uint32_t bits = o0 ^ o1;   // partitionable 32-bit path XORs both lanes
    // uniform(minval=tiny, maxval=1): exact JAX bit trick
    float f = __uint_as_float((bits >> 9) | 0x3f800000u) - 1.0f;
    float u = fmaxf(1.17549435e-38f, f + 1.17549435e-38f);
    // gumbel = -log(-log(u)), each log rounded to f32 (computed via double)
    float t1 = (float)log((double)u);
    float t2 = -t1;
    float t3 = (float)log((double)t2);
    float val = (-t3) + lrow[v];
    if (val > best) { best = val; bestIdx = v; }  // strict > keeps first max
  }

  __shared__ float sv[256];
  __shared__ int   si[256];
  sv[tid] = best; si[tid] = bestIdx;
  __syncthreads();
  for (int s = 128; s > 0; s >>= 1) {
    if (tid < s) {
      float v2 = sv[tid + s]; int i2 = si[tid + s];
      if (v2 > sv[tid] || (v2 == sv[tid] && i2 < si[tid])) { sv[tid] = v2; si[tid] = i2; }
    }
    __syncthreads();
  }
  if (tid == 0) out[b * S_ + col] = si[0];
}

// ---------------------------------------------------------------------------
extern "C" void kernel_launch(void* const* d_in, const int* in_sizes, int n_in,
                              void* d_out, int out_size, void* d_ws, size_t ws_size,
                              hipStream_t stream) {
  const int*   x    = (const int*)  d_in[0];
  // d_in[1] = class_label (unused by reference), d_in[2] = given_num (=64, fixed)
  const float* emb  = (const float*)d_in[3];
  const float* Wih0 = (const float*)d_in[4];
  const float* Whh0 = (const float*)d_in[5];
  const float* bih0 = (const float*)d_in[6];
  const float* bhh0 = (const float*)d_in[7];
  const float* Wih1 = (const float*)d_in[8];
  const float* Whh1 = (const float*)d_in[9];
  const float* bih1 = (const float*)d_in[10];
  const float* bhh1 = (const float*)d_in[11];
  const float* Wlin = (const float*)d_in[12];
  const float* blin = (const float*)d_in[13];
  int* out = (int*)d_out;

  // workspace layout (floats): g/logits buffer reused, then 4 state vectors
  float* ws = (float*)d_ws;
  float* g      = ws;                      // 128*8192 = 1,048,576 (logits reuse)
  float* h0     = g + (size_t)B_ * H4_;    // 262,144 each
  float* c0     = h0 + (size_t)B_ * H_;
  float* h1     = c0 + (size_t)B_ * H_;
  float* c1     = h1 + (size_t)B_ * H_;
  float* logits = g;                       // reuse g (free during logits+sample)
  uint32_t* keys = (uint32_t*)(c1 + (size_t)B_ * H_);

  // zero initial h0,c0,h1,c1 (contiguous)
  hipMemsetAsync(h0, 0, (size_t)4 * B_ * H_ * sizeof(float), stream);
  keys_kernel<<<1, 64, 0, stream>>>(keys);
  copy_prefix<<<(B_ * GIVEN_) / 256, 256, 0, stream>>>(x, out);

  dim3 gridLSTM(H4_ / 64, B_ / 64);   // (128, 2)
  dim3 gridLogit(V_ / 64, B_ / 64);   // (125, 2)

  auto lstm_step = [&](const int* ridx, int rstride) {
    // layer 0: g = emb[tok] @ Wih0^T + h0 @ Whh0^T
    gemm2_nt<<<gridLSTM, 256, 0, stream>>>(emb, E_, ridx, rstride, Wih0, E_,
                                           h0, H_, Whh0, H_, nullptr, g, H4_);
    gates_kernel<<<(B_ * H_) / 256, 256, 0, stream>>>(g, bih0, bhh0, h0, c0);
    // layer 1: g = h0 @ Wih1^T + h1 @ Whh1^T
    gemm2_nt<<<gridLSTM, 256, 0, stream>>>(h0, H_, nullptr, 0, Wih1, H_,
                                           h1, H_, Whh1, H_, nullptr, g, H4_);
    gates_kernel<<<(B_ * H_) / 256, 256, 0, stream>>>(g, bih1, bhh1, h1, c1);
  };

  // teacher forcing: t = 0..63, input token = x[:, t]
  for (int t = 0; t < GIVEN_; ++t) {
    lstm_step(x + t, S_);
  }

  // rollout: 64 steps; step 0 re-uses x[:, GIVEN-1] embedding (per reference)
  for (int t = 0; t < S_ - GIVEN_; ++t) {
    const int* ridx = (t == 0) ? (x + (GIVEN_ - 1)) : (out + (GIVEN_ + t - 1));
    lstm_step(ridx, S_);
    // logits = h1 @ Wlin^T + blin
    gemm2_nt<<<gridLogit, 256, 0, stream>>>(h1, H_, nullptr, 0, Wlin, H_,
                                            h1, H_, nullptr, 0, blin, logits, V_);
    sample_kernel<<<B_, 256, 0, stream>>>(logits, keys, t, out, GIVEN_ + t);
  }
}

// Round 4
// 30530.212 us; speedup vs baseline: 2.3084x; 2.3084x over previous
//
#include <hip/hip_runtime.h>
#include <stdint.h>
#include <math.h>

// Problem constants (fixed by setup_inputs)
#define B_     128
#define S_     128
#define V_     8000
#define E_     512
#define H_     2048
#define H4_    8192
#define GIVEN_ 64

typedef __bf16 bf16x8 __attribute__((ext_vector_type(8)));
typedef float  f32x16 __attribute__((ext_vector_type(16)));
typedef short  short8 __attribute__((ext_vector_type(8)));

// ---------------------------------------------------------------------------
// Threefry-2x32 (20 rounds) — exact JAX semantics
// ---------------------------------------------------------------------------
__device__ __forceinline__ uint32_t rotl32(uint32_t v, int d) {
  return (v << d) | (v >> (32 - d));
}

__device__ __forceinline__ void threefry2x32(uint32_t k0, uint32_t k1,
                                             uint32_t x0, uint32_t x1,
                                             uint32_t& o0, uint32_t& o1) {
  uint32_t k2 = k0 ^ k1 ^ 0x1BD11BDAu;
  x0 += k0; x1 += k1;
#define TF_RND(R) { x0 += x1; x1 = rotl32(x1, (R)); x1 ^= x0; }
  TF_RND(13) TF_RND(15) TF_RND(26) TF_RND(6)
  x0 += k1; x1 += k2 + 1u;
  TF_RND(17) TF_RND(29) TF_RND(16) TF_RND(24)
  x0 += k2; x1 += k0 + 2u;
  TF_RND(13) TF_RND(15) TF_RND(26) TF_RND(6)
  x0 += k0; x1 += k1 + 3u;
  TF_RND(17) TF_RND(29) TF_RND(16) TF_RND(24)
  x0 += k1; x1 += k2 + 4u;
  TF_RND(13) TF_RND(15) TF_RND(26) TF_RND(6)
  x0 += k2; x1 += k0 + 5u;
#undef TF_RND
  o0 = x0; o1 = x1;
}

// keys = jax.random.split(jax.random.key(1), 64), jax_threefry_partitionable:
// keys[t] = threefry2x32(key=(0,1), counter=(0,t)) -> (o0, o1) stacked.
__global__ void keys_kernel(uint32_t* __restrict__ keys) {
  int t = threadIdx.x;  // 0..63
  uint32_t o0, o1;
  threefry2x32(0u, 1u, 0u, (uint32_t)t, o0, o1);
  keys[2 * t]     = o0;
  keys[2 * t + 1] = o1;
}

// out[:, :GIVEN] = x[:, :GIVEN]
__global__ void copy_prefix(const int* __restrict__ x, int* __restrict__ out) {
  int idx = blockIdx.x * blockDim.x + threadIdx.x;  // b*GIVEN + s
  int b = idx >> 6;   // /64
  int s = idx & 63;
  out[b * S_ + s] = x[b * S_ + s];
}

// split f32 -> hi/lo bf16 (truncation; |x-(hi+lo)| <= 2^-16 |x|)
__device__ __forceinline__ void split2(float x, uint16_t& hi, uint16_t& lo) {
  uint32_t xb = __float_as_uint(x);
  hi = (uint16_t)(xb >> 16);
  float l = x - __uint_as_float(xb & 0xFFFF0000u);
  lo = (uint16_t)(__float_as_uint(l) >> 16);
}

// ---------------------------------------------------------------------------
// Split-bf16 MFMA dual GEMM (NT): C = A1 @ W1^T [+ A2 @ W2^T] [+ bias]
// Each f32 operand is split on the fly into hi+lo bf16; accumulate
// Ahi*Bhi + Ahi*Blo + Alo*Bhi with v_mfma_f32_32x32x16_bf16 (f32 acc).
// Block: 256 thr = 4 waves; tile 64(M)x64(N); BK=64.
// Wave w covers 32x32 at (wr,wc) = ((w>>1)*32, (w&1)*32).
// LDS k-chunk-major: arr[(chunk*64 + row)*8 + j], chunk = 8 consecutive k.
//   -> both ds_write_b128 and ds_read_b128 are bank-conflict-free
//      (8 consecutive lanes hit rows r..r+7 => banks 0..31).
// Optional row gather for A1 (embedding lookup fused in).
// ---------------------------------------------------------------------------
__global__ __launch_bounds__(256) void gemm2_mfma(
    const float* __restrict__ A1, int lda1,
    const int* __restrict__ ridx, int ridx_stride,
    const float* __restrict__ W1, int K1,
    const float* __restrict__ A2, int lda2,
    const float* __restrict__ W2, int K2,
    const float* __restrict__ bias,
    float* __restrict__ C, int ldc)
{
  __shared__ __align__(16) uint16_t Ahi[8 * 64 * 8];
  __shared__ __align__(16) uint16_t Alo[8 * 64 * 8];
  __shared__ __align__(16) uint16_t Bhi[8 * 64 * 8];
  __shared__ __align__(16) uint16_t Blo[8 * 64 * 8];

  const int m0   = blockIdx.y * 64;
  const int n0   = blockIdx.x * 64;
  const int tid  = threadIdx.x;
  const int w    = tid >> 6;
  const int wr   = (w >> 1) * 32;
  const int wc   = (w & 1) * 32;
  const int lane = tid & 63;
  const int lrow = lane & 31;
  const int lgrp = lane >> 5;   // 0/1

  // staging role: threads 0..127 stage A-tile, 128..255 stage B-tile.
  const bool isB = (tid >= 128);
  const int  ts  = isB ? (tid - 128) : tid;
  const int  sr  = ts >> 1;          // row 0..63 within tile
  const int  sh  = (ts & 1) * 32;    // k offset (f32 elems): 0 or 32
  const int  cbase = (ts & 1) * 4;   // chunk base: 0 or 4
  uint16_t* dhi = isB ? Bhi : Ahi;
  uint16_t* dlo = isB ? Blo : Alo;

  f32x16 acc = {0,0,0,0, 0,0,0,0, 0,0,0,0, 0,0,0,0};

  for (int phase = 0; phase < 2; ++phase) {
    const int K = phase ? K2 : K1;
    if (K == 0) continue;

    // source row pointer for this thread's staging
    const float* srow;
    if (isB) {
      const float* W = phase ? W2 : W1;
      srow = W + (size_t)(n0 + sr) * K;
    } else if (phase == 0 && ridx) {
      srow = A1 + (size_t)ridx[(size_t)(m0 + sr) * ridx_stride] * lda1;
    } else {
      const float* A   = phase ? A2 : A1;
      const int    lda = phase ? lda2 : lda1;
      srow = A + (size_t)(m0 + sr) * lda;
    }

    for (int k0 = 0; k0 < K; k0 += 64) {
      // ---- load 32 consecutive f32 (128B) per thread ----
      const float* p = srow + k0 + sh;
      float4 q0 = ((const float4*)p)[0];
      float4 q1 = ((const float4*)p)[1];
      float4 q2 = ((const float4*)p)[2];
      float4 q3 = ((const float4*)p)[3];
      float4 q4 = ((const float4*)p)[4];
      float4 q5 = ((const float4*)p)[5];
      float4 q6 = ((const float4*)p)[6];
      float4 q7 = ((const float4*)p)[7];

      __syncthreads();   // previous k-tile's reads complete

      // ---- split + write 4 chunks x (hi,lo) ----
      {
        float e[32];
        e[0]=q0.x; e[1]=q0.y; e[2]=q0.z; e[3]=q0.w;
        e[4]=q1.x; e[5]=q1.y; e[6]=q1.z; e[7]=q1.w;
        e[8]=q2.x; e[9]=q2.y; e[10]=q2.z; e[11]=q2.w;
        e[12]=q3.x; e[13]=q3.y; e[14]=q3.z; e[15]=q3.w;
        e[16]=q4.x; e[17]=q4.y; e[18]=q4.z; e[19]=q4.w;
        e[20]=q5.x; e[21]=q5.y; e[22]=q5.z; e[23]=q5.w;
        e[24]=q6.x; e[25]=q6.y; e[26]=q6.z; e[27]=q6.w;
        e[28]=q7.x; e[29]=q7.y; e[30]=q7.z; e[31]=q7.w;
#pragma unroll
        for (int c = 0; c < 4; ++c) {
          short8 hv, lv;
#pragma unroll
          for (int j = 0; j < 8; ++j) {
            uint16_t h16, l16;
            split2(e[c * 8 + j], h16, l16);
            hv[j] = (short)h16;
            lv[j] = (short)l16;
          }
          const int chunk = cbase + c;
          *(short8*)&dhi[(chunk * 64 + sr) * 8] = hv;
          *(short8*)&dlo[(chunk * 64 + sr) * 8] = lv;
        }
      }

      __syncthreads();   // tile staged

      // ---- MFMA: 4 k-steps of 16 ----
#pragma unroll
      for (int ks = 0; ks < 4; ++ks) {
        const int ca = ks * 2 + lgrp;
        bf16x8 ah = *(const bf16x8*)&Ahi[(ca * 64 + wr + lrow) * 8];
        bf16x8 al = *(const bf16x8*)&Alo[(ca * 64 + wr + lrow) * 8];
        bf16x8 bh = *(const bf16x8*)&Bhi[(ca * 64 + wc + lrow) * 8];
        bf16x8 bl = *(const bf16x8*)&Blo[(ca * 64 + wc + lrow) * 8];
        acc = __builtin_amdgcn_mfma_f32_32x32x16_bf16(ah, bh, acc, 0, 0, 0);
        acc = __builtin_amdgcn_mfma_f32_32x32x16_bf16(ah, bl, acc, 0, 0, 0);
        acc = __builtin_amdgcn_mfma_f32_32x32x16_bf16(al, bh, acc, 0, 0, 0);
      }
    }
  }

  // ---- epilogue: C/D layout col=lane&31, row=(reg&3)+8*(reg>>2)+4*lgrp ----
  const int col = n0 + wc + lrow;
  const float bv = bias ? bias[col] : 0.0f;
#pragma unroll
  for (int rg = 0; rg < 4; ++rg) {
#pragma unroll
    for (int rr = 0; rr < 4; ++rr) {
      const int row = m0 + wr + rr + 8 * rg + 4 * lgrp;
      C[(size_t)row * ldc + col] = acc[rg * 4 + rr] + bv;
    }
  }
}

// ---------------------------------------------------------------------------
// LSTM gate update: g is (B x 4H) pre-activation WITHOUT bias; biases added
// here. Gate order from jnp.split: i, f, g, o.
// ---------------------------------------------------------------------------
__global__ __launch_bounds__(256) void gates_kernel(
    const float* __restrict__ g, const float* __restrict__ bih,
    const float* __restrict__ bhh, float* __restrict__ h, float* __restrict__ c)
{
  int idx = blockIdx.x * blockDim.x + threadIdx.x;  // b*H + n
  int b = idx >> 11;   // / 2048
  int n = idx & (H_ - 1);
  const float* gb = g + (size_t)b * H4_;
  float gi = gb[n]           + bih[n]           + bhh[n];
  float gf = gb[n + H_]      + bih[n + H_]      + bhh[n + H_];
  float gg = gb[n + 2 * H_]  + bih[n + 2 * H_]  + bhh[n + 2 * H_];
  float go = gb[n + 3 * H_]  + bih[n + 3 * H_]  + bhh[n + 3 * H_];
  float si = 1.f / (1.f + expf(-gi));
  float sf = 1.f / (1.f + expf(-gf));
  float so = 1.f / (1.f + expf(-go));
  float cv = sf * c[idx] + si * tanhf(gg);
  c[idx] = cv;
  h[idx] = so * tanhf(cv);
}

// ---------------------------------------------------------------------------
// categorical sampling: argmax_v (logits[b][v] + gumbel[b][v]).
// jax_threefry_partitionable 32-bit bits: bits[j] = o0 ^ o1 of
// threefry2x32(key_t, (0, j)).  First-index tie-break.
// ---------------------------------------------------------------------------
__global__ __launch_bounds__(256) void sample_kernel(
    const float* __restrict__ logits, const uint32_t* __restrict__ keys,
    int t, int* __restrict__ out, int col)
{
  const int b = blockIdx.x;
  const int tid = threadIdx.x;
  const uint32_t k0 = keys[2 * t];
  const uint32_t k1 = keys[2 * t + 1];
  const float* lrow = logits + (size_t)b * V_;

  float best = -3.4e38f;
  int bestIdx = 0;
  for (int v = tid; v < V_; v += 256) {
    uint32_t j = (uint32_t)(b * V_ + v);
    uint32_t o0, o1;
    threefry2x32(k0, k1, 0u, j, o0, o1);
    uint32_t bits = o0 ^ o1;
    float f = __uint_as_float((bits >> 9) | 0x3f800000u) - 1.0f;
    float u = fmaxf(1.17549435e-38f, f + 1.17549435e-38f);
    float t1 = (float)log((double)u);
    float t2 = -t1;
    float t3 = (float)log((double)t2);
    float val = (-t3) + lrow[v];
    if (val > best) { best = val; bestIdx = v; }
  }

  __shared__ float sv[256];
  __shared__ int   si[256];
  sv[tid] = best; si[tid] = bestIdx;
  __syncthreads();
  for (int s = 128; s > 0; s >>= 1) {
    if (tid < s) {
      float v2 = sv[tid + s]; int i2 = si[tid + s];
      if (v2 > sv[tid] || (v2 == sv[tid] && i2 < si[tid])) { sv[tid] = v2; si[tid] = i2; }
    }
    __syncthreads();
  }
  if (tid == 0) out[b * S_ + col] = si[0];
}

// ---------------------------------------------------------------------------
extern "C" void kernel_launch(void* const* d_in, const int* in_sizes, int n_in,
                              void* d_out, int out_size, void* d_ws, size_t ws_size,
                              hipStream_t stream) {
  const int*   x    = (const int*)  d_in[0];
  const float* emb  = (const float*)d_in[3];
  const float* Wih0 = (const float*)d_in[4];
  const float* Whh0 = (const float*)d_in[5];
  const float* bih0 = (const float*)d_in[6];
  const float* bhh0 = (const float*)d_in[7];
  const float* Wih1 = (const float*)d_in[8];
  const float* Whh1 = (const float*)d_in[9];
  const float* bih1 = (const float*)d_in[10];
  const float* bhh1 = (const float*)d_in[11];
  const float* Wlin = (const float*)d_in[12];
  const float* blin = (const float*)d_in[13];
  int* out = (int*)d_out;

  float* ws = (float*)d_ws;
  float* g      = ws;                      // 128*8192 (logits reuse)
  float* h0     = g + (size_t)B_ * H4_;
  float* c0     = h0 + (size_t)B_ * H_;
  float* h1     = c0 + (size_t)B_ * H_;
  float* c1     = h1 + (size_t)B_ * H_;
  float* logits = g;
  uint32_t* keys = (uint32_t*)(c1 + (size_t)B_ * H_);

  hipMemsetAsync(h0, 0, (size_t)4 * B_ * H_ * sizeof(float), stream);
  keys_kernel<<<1, 64, 0, stream>>>(keys);
  copy_prefix<<<(B_ * GIVEN_) / 256, 256, 0, stream>>>(x, out);

  dim3 gridLSTM(H4_ / 64, B_ / 64);   // (128, 2)
  dim3 gridLogit(V_ / 64, B_ / 64);   // (125, 2)

  auto lstm_step = [&](const int* ridx, int rstride) {
    gemm2_mfma<<<gridLSTM, 256, 0, stream>>>(emb, E_, ridx, rstride, Wih0, E_,
                                             h0, H_, Whh0, H_, nullptr, g, H4_);
    gates_kernel<<<(B_ * H_) / 256, 256, 0, stream>>>(g, bih0, bhh0, h0, c0);
    gemm2_mfma<<<gridLSTM, 256, 0, stream>>>(h0, H_, nullptr, 0, Wih1, H_,
                                             h1, H_, Whh1, H_, nullptr, g, H4_);
    gates_kernel<<<(B_ * H_) / 256, 256, 0, stream>>>(g, bih1, bhh1, h1, c1);
  };

  for (int t = 0; t < GIVEN_; ++t) {
    lstm_step(x + t, S_);
  }

  for (int t = 0; t < S_ - GIVEN_; ++t) {
    const int* ridx = (t == 0) ? (x + (GIVEN_ - 1)) : (out + (GIVEN_ + t - 1));
    lstm_step(ridx, S_);
    gemm2_mfma<<<gridLogit, 256, 0, stream>>>(h1, H_, nullptr, 0, Wlin, H_,
                                              h1, H_, nullptr, 0, blin, logits, V_);
    sample_kernel<<<B_, 256, 0, stream>>>(logits, keys, t, out, GIVEN_ + t);
  }
}

// Round 6
// 14567.596 us; speedup vs baseline: 4.8378x; 2.0958x over previous
//
#include <hip/hip_runtime.h>
#include <stdint.h>
#include <math.h>

// Problem constants (fixed by setup_inputs)
#define B_     128
#define S_     128
#define V_     8000
#define E_     512
#define H_     2048
#define H4_    8192
#define GIVEN_ 64

typedef __bf16 bf16x8 __attribute__((ext_vector_type(8)));
typedef float  f32x16 __attribute__((ext_vector_type(16)));
typedef short  short8 __attribute__((ext_vector_type(8)));

// ---------------------------------------------------------------------------
// Threefry-2x32 (20 rounds) — exact JAX semantics (verified passing r3/r4)
// ---------------------------------------------------------------------------
__device__ __forceinline__ uint32_t rotl32(uint32_t v, int d) {
  return (v << d) | (v >> (32 - d));
}

__device__ __forceinline__ void threefry2x32(uint32_t k0, uint32_t k1,
                                             uint32_t x0, uint32_t x1,
                                             uint32_t& o0, uint32_t& o1) {
  uint32_t k2 = k0 ^ k1 ^ 0x1BD11BDAu;
  x0 += k0; x1 += k1;
#define TF_RND(R) { x0 += x1; x1 = rotl32(x1, (R)); x1 ^= x0; }
  TF_RND(13) TF_RND(15) TF_RND(26) TF_RND(6)
  x0 += k1; x1 += k2 + 1u;
  TF_RND(17) TF_RND(29) TF_RND(16) TF_RND(24)
  x0 += k2; x1 += k0 + 2u;
  TF_RND(13) TF_RND(15) TF_RND(26) TF_RND(6)
  x0 += k0; x1 += k1 + 3u;
  TF_RND(17) TF_RND(29) TF_RND(16) TF_RND(24)
  x0 += k1; x1 += k2 + 4u;
  TF_RND(13) TF_RND(15) TF_RND(26) TF_RND(6)
  x0 += k2; x1 += k0 + 5u;
#undef TF_RND
  o0 = x0; o1 = x1;
}

__global__ void keys_kernel(uint32_t* __restrict__ keys) {
  int t = threadIdx.x;  // 0..63
  uint32_t o0, o1;
  threefry2x32(0u, 1u, 0u, (uint32_t)t, o0, o1);
  keys[2 * t]     = o0;
  keys[2 * t + 1] = o1;
}

__global__ void copy_prefix(const int* __restrict__ x, int* __restrict__ out) {
  int idx = blockIdx.x * blockDim.x + threadIdx.x;
  int b = idx >> 6;
  int s = idx & 63;
  out[b * S_ + s] = x[b * S_ + s];
}

// split f32 -> hi/lo bf16 (truncation; identical math to passing rounds 3/4)
__device__ __forceinline__ void split2(float x, uint16_t& hi, uint16_t& lo) {
  uint32_t xb = __float_as_uint(x);
  hi = (uint16_t)(xb >> 16);
  float l = x - __uint_as_float(xb & 0xFFFF0000u);
  lo = (uint16_t)(__float_as_uint(l) >> 16);
}

__device__ __forceinline__ void splitpack(float4 a, float4 b,
                                          bf16x8& hi, bf16x8& lo) {
  float e[8] = {a.x, a.y, a.z, a.w, b.x, b.y, b.z, b.w};
  short8 h, l;
#pragma unroll
  for (int j = 0; j < 8; ++j) {
    uint16_t h16, l16;
    split2(e[j], h16, l16);
    h[j] = (short)h16;
    l[j] = (short)l16;
  }
  hi = __builtin_bit_cast(bf16x8, h);
  lo = __builtin_bit_cast(bf16x8, l);
}

#define MFMA_(a, b, c) __builtin_amdgcn_mfma_f32_32x32x16_bf16(a, b, c, 0, 0, 0)

// ---------------------------------------------------------------------------
// One GEMM phase: acc[4] += A(128 x K) @ W(N x K)^T restricted to this
// block's 32 output cols. A either gathered-f32 (emb rows via ridx, split
// in-register) or pre-split staged-h (bf16 hi/lo in MFMA fragment layout).
// W loaded as f32 rows, split in-register (same bytes as bf16 hi/lo pair).
// 4 waves split K; wave w takes k16-steps w, w+4, w+8, ...
// staged-h layout: elem(b,n) at ((n>>4)*4+(b>>5))*512 + ((n>>3)&1)*256
//                              + (b&31)*8 + (n&7)
// ---------------------------------------------------------------------------
template<bool GATHER>
__device__ __forceinline__ void run_phase(
    f32x16 (&acc)[4],
    const float* __restrict__ aF,
    const uint16_t* __restrict__ aHi, const uint16_t* __restrict__ aLo,
    const int* __restrict__ ridx, int rstride,
    const float* __restrict__ W, int K, bool gateRe,
    int jb, int w, int lrow, int lgrp)
{
  const int nFS = K >> 6;   // K/16 k-steps, /4 waves
  // B row for this lane's output column (lrow in [0,32))
  const int wrow = gateRe ? ((lrow >> 3) * H_ + jb * 8 + (lrow & 7))
                          : (jb * 32 + lrow);
  const float* bptr = W + (size_t)wrow * K + lgrp * 8;

  size_t aoff0, aoff1, aoff2, aoff3;
  if (GATHER) {
    aoff0 = (size_t)ridx[(size_t)(lrow)      * rstride] * E_ + lgrp * 8;
    aoff1 = (size_t)ridx[(size_t)(32 + lrow) * rstride] * E_ + lgrp * 8;
    aoff2 = (size_t)ridx[(size_t)(64 + lrow) * rstride] * E_ + lgrp * 8;
    aoff3 = (size_t)ridx[(size_t)(96 + lrow) * rstride] * E_ + lgrp * 8;
  } else {
    aoff0 = (size_t)lgrp * 256 + (size_t)lrow * 8;
    aoff1 = aoff0 + 512;
    aoff2 = aoff0 + 1024;
    aoff3 = aoff0 + 1536;
  }

  // double-buffered raw operands (all statically indexed — no scratch)
  float4 bR0[2], bR1[2];
  float4 gR0[2][2], gR1[2][2], gR2[2][2], gR3[2][2];
  bf16x8 sh0[2], sh1[2], sh2[2], sh3[2], sl0[2], sl1[2], sl2[2], sl3[2];

#define LOADFS(BUF, KS)                                                      \
  {                                                                          \
    const float* bp = bptr + (size_t)(KS) * 16;                              \
    bR0[BUF] = ((const float4*)bp)[0];                                       \
    bR1[BUF] = ((const float4*)bp)[1];                                       \
    if (GATHER) {                                                            \
      const float* a0 = aF + aoff0 + (size_t)(KS) * 16;                      \
      const float* a1 = aF + aoff1 + (size_t)(KS) * 16;                      \
      const float* a2 = aF + aoff2 + (size_t)(KS) * 16;                      \
      const float* a3 = aF + aoff3 + (size_t)(KS) * 16;                      \
      gR0[BUF][0] = ((const float4*)a0)[0]; gR0[BUF][1] = ((const float4*)a0)[1]; \
      gR1[BUF][0] = ((const float4*)a1)[0]; gR1[BUF][1] = ((const float4*)a1)[1]; \
      gR2[BUF][0] = ((const float4*)a2)[0]; gR2[BUF][1] = ((const float4*)a2)[1]; \
      gR3[BUF][0] = ((const float4*)a3)[0]; gR3[BUF][1] = ((const float4*)a3)[1]; \
    } else {                                                                 \
      size_t o0 = aoff0 + (size_t)(KS) * 2048;                               \
      size_t o1 = aoff1 + (size_t)(KS) * 2048;                               \
      size_t o2 = aoff2 + (size_t)(KS) * 2048;                               \
      size_t o3 = aoff3 + (size_t)(KS) * 2048;                               \
      sh0[BUF] = *(const bf16x8*)(aHi + o0); sl0[BUF] = *(const bf16x8*)(aLo + o0); \
      sh1[BUF] = *(const bf16x8*)(aHi + o1); sl1[BUF] = *(const bf16x8*)(aLo + o1); \
      sh2[BUF] = *(const bf16x8*)(aHi + o2); sl2[BUF] = *(const bf16x8*)(aLo + o2); \
      sh3[BUF] = *(const bf16x8*)(aHi + o3); sl3[BUF] = *(const bf16x8*)(aLo + o3); \
    }                                                                        \
  }

#define COMPFS(BUF)                                                          \
  {                                                                          \
    bf16x8 bh, bl;                                                           \
    splitpack(bR0[BUF], bR1[BUF], bh, bl);                                   \
    bf16x8 ah, al;                                                           \
    if (GATHER) splitpack(gR0[BUF][0], gR0[BUF][1], ah, al);                 \
    else { ah = sh0[BUF]; al = sl0[BUF]; }                                   \
    acc[0] = MFMA_(ah, bh, acc[0]);                                          \
    acc[0] = MFMA_(ah, bl, acc[0]);                                          \
    acc[0] = MFMA_(al, bh, acc[0]);                                          \
    if (GATHER) splitpack(gR1[BUF][0], gR1[BUF][1], ah, al);                 \
    else { ah = sh1[BUF]; al = sl1[BUF]; }                                   \
    acc[1] = MFMA_(ah, bh, acc[1]);                                          \
    acc[1] = MFMA_(ah, bl, acc[1]);                                          \
    acc[1] = MFMA_(al, bh, acc[1]);                                          \
    if (GATHER) splitpack(gR2[BUF][0], gR2[BUF][1], ah, al);                 \
    else { ah = sh2[BUF]; al = sl2[BUF]; }                                   \
    acc[2] = MFMA_(ah, bh, acc[2]);                                          \
    acc[2] = MFMA_(ah, bl, acc[2]);                                          \
    acc[2] = MFMA_(al, bh, acc[2]);                                          \
    if (GATHER) splitpack(gR3[BUF][0], gR3[BUF][1], ah, al);                 \
    else { ah = sh3[BUF]; al = sl3[BUF]; }                                   \
    acc[3] = MFMA_(ah, bh, acc[3]);                                          \
    acc[3] = MFMA_(ah, bl, acc[3]);                                          \
    acc[3] = MFMA_(al, bh, acc[3]);                                          \
  }

  int ks = w;
  LOADFS(0, ks); ks += 4;
  int rem = nFS;              // nFS is even (8 or 32)
  while (rem >= 2) {
    LOADFS(1, ks); ks += 4;
    COMPFS(0);
    if (rem > 2) { LOADFS(0, ks); ks += 4; }
    COMPFS(1);
    rem -= 2;
  }
#undef LOADFS
#undef COMPFS
}

// ---------------------------------------------------------------------------
// Fused dual-GEMM + epilogue. Tile: M=128 (all batch) x N=32. Grid 1-D over
// 32-col blocks. 4 waves K-split -> 64KB LDS reduce (XOR bank swizzle).
//   EPI=1: LSTM gates (bias add, sigmoid/tanh, c RMW, h -> pre-split staged)
//          block jb owns hidden units jb*8..jb*8+7; cols = gate*8 + unit.
//   EPI=0: bias add + f32 store (logits).
// ---------------------------------------------------------------------------
template<int EPI, int GATHER1>
__global__ __launch_bounds__(256) void gemm_ks(
    const float* __restrict__ a1F,
    const uint16_t* __restrict__ a1Hi, const uint16_t* __restrict__ a1Lo,
    const int* __restrict__ ridx, int rstride,
    const float* __restrict__ W1, int K1,
    const uint16_t* __restrict__ a2Hi, const uint16_t* __restrict__ a2Lo,
    const float* __restrict__ W2, int K2,
    const float* __restrict__ bih, const float* __restrict__ bhh,
    float* __restrict__ cState,
    uint16_t* __restrict__ hOutHi, uint16_t* __restrict__ hOutLo,
    const float* __restrict__ bias, float* __restrict__ Cout)
{
  __shared__ float red[4][128 * 32];   // exactly 64 KiB

  const int jb   = blockIdx.x;
  const int tid  = threadIdx.x;
  const int w    = tid >> 6;
  const int lane = tid & 63;
  const int lrow = lane & 31;
  const int lgrp = lane >> 5;

  f32x16 acc[4];
#pragma unroll
  for (int mf = 0; mf < 4; ++mf)
#pragma unroll
    for (int r = 0; r < 16; ++r) acc[mf][r] = 0.0f;

  run_phase<GATHER1 != 0>(acc, a1F, a1Hi, a1Lo, ridx, rstride,
                          W1, K1, EPI == 1, jb, w, lrow, lgrp);
  if (K2 > 0)
    run_phase<false>(acc, nullptr, a2Hi, a2Lo, nullptr, 0,
                     W2, K2, EPI == 1, jb, w, lrow, lgrp);

  // partials -> LDS (write: conflict-free via col XOR row swizzle)
#pragma unroll
  for (int mf = 0; mf < 4; ++mf)
#pragma unroll
    for (int r = 0; r < 16; ++r) {
      const int row = mf * 32 + (r & 3) + 8 * (r >> 2) + 4 * lgrp;
      red[w][row * 32 + (lrow ^ (row & 31))] = acc[mf][r];
    }
  __syncthreads();

  if constexpr (EPI == 1) {
    const int b  = tid & 127;
    const int uh = tid >> 7;
#pragma unroll
    for (int q = 0; q < 4; ++q) {
      const int u = uh * 4 + q;
      float gs[4];
#pragma unroll
      for (int g = 0; g < 4; ++g) {
        const int cs = (g * 8 + u) ^ (b & 31);
        gs[g] = ((red[0][b * 32 + cs] + red[1][b * 32 + cs])
                 + red[2][b * 32 + cs]) + red[3][b * 32 + cs];
      }
      const int n = jb * 8 + u;
      float gi = gs[0] + bih[n]          + bhh[n];
      float gf = gs[1] + bih[H_ + n]     + bhh[H_ + n];
      float gg = gs[2] + bih[2 * H_ + n] + bhh[2 * H_ + n];
      float go = gs[3] + bih[3 * H_ + n] + bhh[3 * H_ + n];
      float si = 1.f / (1.f + expf(-gi));
      float sf = 1.f / (1.f + expf(-gf));
      float so = 1.f / (1.f + expf(-go));
      const size_t ci = (size_t)b * H_ + n;
      float cv = sf * cState[ci] + si * tanhf(gg);
      cState[ci] = cv;
      float hv = so * tanhf(cv);
      uint16_t hh, hl;
      split2(hv, hh, hl);
      const size_t hoff = (size_t)((n >> 4) * 4 + (b >> 5)) * 512
                        + (size_t)((n >> 3) & 1) * 256
                        + (size_t)(b & 31) * 8 + (size_t)(n & 7);
      hOutHi[hoff] = hh;
      hOutLo[hoff] = hl;
    }
  } else {
    const int b  = tid & 127;
    const int ch = (tid >> 7) * 16;
#pragma unroll
    for (int q = 0; q < 16; ++q) {
      const int col = ch + q;
      const int cs = col ^ (b & 31);
      float v = ((red[0][b * 32 + cs] + red[1][b * 32 + cs])
                 + red[2][b * 32 + cs]) + red[3][b * 32 + cs];
      Cout[(size_t)b * V_ + jb * 32 + col] = v + bias[jb * 32 + col];
    }
  }
}

// ---------------------------------------------------------------------------
// categorical sampling (verbatim from passing rounds 3/4)
// ---------------------------------------------------------------------------
__global__ __launch_bounds__(256) void sample_kernel(
    const float* __restrict__ logits, const uint32_t* __restrict__ keys,
    int t, int* __restrict__ out, int col)
{
  const int b = blockIdx.x;
  const int tid = threadIdx.x;
  const uint32_t k0 = keys[2 * t];
  const uint32_t k1 = keys[2 * t + 1];
  const float* lrow = logits + (size_t)b * V_;

  float best = -3.4e38f;
  int bestIdx = 0;
  for (int v = tid; v < V_; v += 256) {
    uint32_t j = (uint32_t)(b * V_ + v);
    uint32_t o0, o1;
    threefry2x32(k0, k1, 0u, j, o0, o1);
    uint32_t bits = o0 ^ o1;
    float f = __uint_as_float((bits >> 9) | 0x3f800000u) - 1.0f;
    float u = fmaxf(1.17549435e-38f, f + 1.17549435e-38f);
    float t1 = (float)log((double)u);
    float t2 = -t1;
    float t3 = (float)log((double)t2);
    float val = (-t3) + lrow[v];
    if (val > best) { best = val; bestIdx = v; }
  }

  __shared__ float sv[256];
  __shared__ int   si[256];
  sv[tid] = best; si[tid] = bestIdx;
  __syncthreads();
  for (int s = 128; s > 0; s >>= 1) {
    if (tid < s) {
      float v2 = sv[tid + s]; int i2 = si[tid + s];
      if (v2 > sv[tid] || (v2 == sv[tid] && i2 < si[tid])) { sv[tid] = v2; si[tid] = i2; }
    }
    __syncthreads();
  }
  if (tid == 0) out[b * S_ + col] = si[0];
}

// ---------------------------------------------------------------------------
extern "C" void kernel_launch(void* const* d_in, const int* in_sizes, int n_in,
                              void* d_out, int out_size, void* d_ws, size_t ws_size,
                              hipStream_t stream) {
  const int*   x    = (const int*)  d_in[0];
  const float* emb  = (const float*)d_in[3];
  const float* Wih0 = (const float*)d_in[4];
  const float* Whh0 = (const float*)d_in[5];
  const float* bih0 = (const float*)d_in[6];
  const float* bhh0 = (const float*)d_in[7];
  const float* Wih1 = (const float*)d_in[8];
  const float* Whh1 = (const float*)d_in[9];
  const float* bih1 = (const float*)d_in[10];
  const float* bhh1 = (const float*)d_in[11];
  const float* Wlin = (const float*)d_in[12];
  const float* blin = (const float*)d_in[13];
  int* out = (int*)d_out;

  // ---- workspace carve-up (~9.9 MB total) ----
  char* wp = (char*)d_ws;
  size_t o = 0;
  auto alloc = [&](size_t bytes) {
    void* p = wp + o; o += (bytes + 255) & ~(size_t)255; return p;
  };
  float*    logits = (float*)   alloc((size_t)B_ * V_ * 4);
  uint32_t* keys   = (uint32_t*)alloc(512);
  float*    c0     = (float*)   alloc((size_t)B_ * H_ * 4);   // zero-block start
  float*    c1     = (float*)   alloc((size_t)B_ * H_ * 4);
  uint16_t* hS0hi[2]; uint16_t* hS0lo[2]; uint16_t* hS1hi[2]; uint16_t* hS1lo[2];
  for (int i = 0; i < 2; ++i) hS0hi[i] = (uint16_t*)alloc((size_t)B_ * H_ * 2);
  for (int i = 0; i < 2; ++i) hS0lo[i] = (uint16_t*)alloc((size_t)B_ * H_ * 2);
  for (int i = 0; i < 2; ++i) hS1hi[i] = (uint16_t*)alloc((size_t)B_ * H_ * 2);
  for (int i = 0; i < 2; ++i) hS1lo[i] = (uint16_t*)alloc((size_t)B_ * H_ * 2);
  size_t zeroBytes = (size_t)((char*)hS1lo[1] + (size_t)B_ * H_ * 2 - (char*)c0);

  hipMemsetAsync(c0, 0, zeroBytes, stream);
  keys_kernel<<<1, 64, 0, stream>>>(keys);
  copy_prefix<<<(B_ * GIVEN_) / 256, 256, 0, stream>>>(x, out);

  int p = 0;
  auto lstm_step = [&](const int* ridx) {
    // layer 0: [emb-gather] @ Wih0^T + h0 @ Whh0^T -> gates -> h0', c0
    gemm_ks<1, 1><<<H_ / 8, 256, 0, stream>>>(
        emb, nullptr, nullptr, ridx, S_, Wih0, E_,
        hS0hi[p], hS0lo[p], Whh0, H_,
        bih0, bhh0, c0, hS0hi[p ^ 1], hS0lo[p ^ 1], nullptr, nullptr);
    // layer 1: h0' @ Wih1^T + h1 @ Whh1^T -> gates -> h1', c1
    gemm_ks<1, 0><<<H_ / 8, 256, 0, stream>>>(
        nullptr, hS0hi[p ^ 1], hS0lo[p ^ 1], nullptr, 0, Wih1, H_,
        hS1hi[p], hS1lo[p], Whh1, H_,
        bih1, bhh1, c1, hS1hi[p ^ 1], hS1lo[p ^ 1], nullptr, nullptr);
    p ^= 1;
  };

  // teacher forcing
  for (int t = 0; t < GIVEN_; ++t) {
    lstm_step(x + t);
  }

  // rollout
  for (int t = 0; t < S_ - GIVEN_; ++t) {
    const int* ridx = (t == 0) ? (x + (GIVEN_ - 1)) : (out + (GIVEN_ + t - 1));
    lstm_step(ridx);
    gemm_ks<0, 0><<<V_ / 32, 256, 0, stream>>>(
        nullptr, hS1hi[p], hS1lo[p], nullptr, 0, Wlin, H_,
        nullptr, nullptr, nullptr, 0,
        nullptr, nullptr, nullptr, nullptr, nullptr, blin, logits);
    sample_kernel<<<B_, 256, 0, stream>>>(logits, keys, t, out, GIVEN_ + t);
  }
}

// Round 7
// 14248.730 us; speedup vs baseline: 4.9460x; 1.0224x over previous
//
#include <hip/hip_runtime.h>
#include <stdint.h>
#include <math.h>

// Problem constants (fixed by setup_inputs)
#define B_     128
#define S_     128
#define V_     8000
#define E_     512
#define H_     2048
#define H4_    8192
#define GIVEN_ 64

typedef __bf16 bf16x8 __attribute__((ext_vector_type(8)));
typedef float  f32x16 __attribute__((ext_vector_type(16)));
typedef short  short8 __attribute__((ext_vector_type(8)));

// ---------------------------------------------------------------------------
// Threefry-2x32 (20 rounds) — exact JAX semantics (verified passing r3/r4/r6)
// ---------------------------------------------------------------------------
__device__ __forceinline__ uint32_t rotl32(uint32_t v, int d) {
  return (v << d) | (v >> (32 - d));
}

__device__ __forceinline__ void threefry2x32(uint32_t k0, uint32_t k1,
                                             uint32_t x0, uint32_t x1,
                                             uint32_t& o0, uint32_t& o1) {
  uint32_t k2 = k0 ^ k1 ^ 0x1BD11BDAu;
  x0 += k0; x1 += k1;
#define TF_RND(R) { x0 += x1; x1 = rotl32(x1, (R)); x1 ^= x0; }
  TF_RND(13) TF_RND(15) TF_RND(26) TF_RND(6)
  x0 += k1; x1 += k2 + 1u;
  TF_RND(17) TF_RND(29) TF_RND(16) TF_RND(24)
  x0 += k2; x1 += k0 + 2u;
  TF_RND(13) TF_RND(15) TF_RND(26) TF_RND(6)
  x0 += k0; x1 += k1 + 3u;
  TF_RND(17) TF_RND(29) TF_RND(16) TF_RND(24)
  x0 += k1; x1 += k2 + 4u;
  TF_RND(13) TF_RND(15) TF_RND(26) TF_RND(6)
  x0 += k2; x1 += k0 + 5u;
#undef TF_RND
  o0 = x0; o1 = x1;
}

__global__ void keys_kernel(uint32_t* __restrict__ keys) {
  int t = threadIdx.x;  // 0..63
  uint32_t o0, o1;
  threefry2x32(0u, 1u, 0u, (uint32_t)t, o0, o1);
  keys[2 * t]     = o0;
  keys[2 * t + 1] = o1;
}

__global__ void copy_prefix(const int* __restrict__ x, int* __restrict__ out) {
  int idx = blockIdx.x * blockDim.x + threadIdx.x;
  int b = idx >> 6;
  int s = idx & 63;
  out[b * S_ + s] = x[b * S_ + s];
}

// split f32 -> hi/lo bf16 (truncation; identical math to passing rounds)
__device__ __forceinline__ void split2(float x, uint16_t& hi, uint16_t& lo) {
  uint32_t xb = __float_as_uint(x);
  hi = (uint16_t)(xb >> 16);
  float l = x - __uint_as_float(xb & 0xFFFF0000u);
  lo = (uint16_t)(__float_as_uint(l) >> 16);
}

__device__ __forceinline__ void splitpack(float4 a, float4 b,
                                          bf16x8& hi, bf16x8& lo) {
  float e[8] = {a.x, a.y, a.z, a.w, b.x, b.y, b.z, b.w};
  short8 h, l;
#pragma unroll
  for (int j = 0; j < 8; ++j) {
    uint16_t h16, l16;
    split2(e[j], h16, l16);
    h[j] = (short)h16;
    l[j] = (short)l16;
  }
  hi = __builtin_bit_cast(bf16x8, h);
  lo = __builtin_bit_cast(bf16x8, l);
}

#define MFMA_(a, b, c) __builtin_amdgcn_mfma_f32_32x32x16_bf16(a, b, c, 0, 0, 0)

// ---------------------------------------------------------------------------
// One GEMM phase: acc[4] += A(128 x K) @ W(N x K)^T restricted to this
// block's 32 output cols. A either gathered-f32 (emb rows via ridx, split
// in-register) or pre-split staged-h (bf16 hi/lo in MFMA fragment layout).
// W loaded as f32 rows, split in-register.
// 8 waves split K; wave w takes k16-steps w, w+8, w+16, ...
// staged-h layout: elem(b,n) at ((n>>4)*4+(b>>5))*512 + ((n>>3)&1)*256
//                              + (b&31)*8 + (n&7)
// ---------------------------------------------------------------------------
template<bool GATHER>
__device__ __forceinline__ void run_phase(
    f32x16 (&acc)[4],
    const float* __restrict__ aF,
    const uint16_t* __restrict__ aHi, const uint16_t* __restrict__ aLo,
    const int* __restrict__ ridx, int rstride,
    const float* __restrict__ W, int K, bool gateRe,
    int jb, int w, int lrow, int lgrp)
{
  const int nFS = K >> 7;   // K/16 k-steps, /8 waves
  // B row for this lane's output column (lrow in [0,32))
  const int wrow = gateRe ? ((lrow >> 3) * H_ + jb * 8 + (lrow & 7))
                          : (jb * 32 + lrow);
  const float* bptr = W + (size_t)wrow * K + lgrp * 8;

  size_t aoff0, aoff1, aoff2, aoff3;
  if (GATHER) {
    aoff0 = (size_t)ridx[(size_t)(lrow)      * rstride] * E_ + lgrp * 8;
    aoff1 = (size_t)ridx[(size_t)(32 + lrow) * rstride] * E_ + lgrp * 8;
    aoff2 = (size_t)ridx[(size_t)(64 + lrow) * rstride] * E_ + lgrp * 8;
    aoff3 = (size_t)ridx[(size_t)(96 + lrow) * rstride] * E_ + lgrp * 8;
  } else {
    aoff0 = (size_t)lgrp * 256 + (size_t)lrow * 8;
    aoff1 = aoff0 + 512;
    aoff2 = aoff0 + 1024;
    aoff3 = aoff0 + 1536;
  }

  // double-buffered raw operands (all statically indexed — no scratch)
  float4 bR0[2], bR1[2];
  float4 gR0[2][2], gR1[2][2], gR2[2][2], gR3[2][2];
  bf16x8 sh0[2], sh1[2], sh2[2], sh3[2], sl0[2], sl1[2], sl2[2], sl3[2];

#define LOADFS(BUF, KS)                                                      \
  {                                                                          \
    const float* bp = bptr + (size_t)(KS) * 16;                              \
    bR0[BUF] = ((const float4*)bp)[0];                                       \
    bR1[BUF] = ((const float4*)bp)[1];                                       \
    if (GATHER) {                                                            \
      const float* a0 = aF + aoff0 + (size_t)(KS) * 16;                      \
      const float* a1 = aF + aoff1 + (size_t)(KS) * 16;                      \
      const float* a2 = aF + aoff2 + (size_t)(KS) * 16;                      \
      const float* a3 = aF + aoff3 + (size_t)(KS) * 16;                      \
      gR0[BUF][0] = ((const float4*)a0)[0]; gR0[BUF][1] = ((const float4*)a0)[1]; \
      gR1[BUF][0] = ((const float4*)a1)[0]; gR1[BUF][1] = ((const float4*)a1)[1]; \
      gR2[BUF][0] = ((const float4*)a2)[0]; gR2[BUF][1] = ((const float4*)a2)[1]; \
      gR3[BUF][0] = ((const float4*)a3)[0]; gR3[BUF][1] = ((const float4*)a3)[1]; \
    } else {                                                                 \
      size_t o0 = aoff0 + (size_t)(KS) * 2048;                               \
      size_t o1 = aoff1 + (size_t)(KS) * 2048;                               \
      size_t o2 = aoff2 + (size_t)(KS) * 2048;                               \
      size_t o3 = aoff3 + (size_t)(KS) * 2048;                               \
      sh0[BUF] = *(const bf16x8*)(aHi + o0); sl0[BUF] = *(const bf16x8*)(aLo + o0); \
      sh1[BUF] = *(const bf16x8*)(aHi + o1); sl1[BUF] = *(const bf16x8*)(aLo + o1); \
      sh2[BUF] = *(const bf16x8*)(aHi + o2); sl2[BUF] = *(const bf16x8*)(aLo + o2); \
      sh3[BUF] = *(const bf16x8*)(aHi + o3); sl3[BUF] = *(const bf16x8*)(aLo + o3); \
    }                                                                        \
  }

#define COMPFS(BUF)                                                          \
  {                                                                          \
    bf16x8 bh, bl;                                                           \
    splitpack(bR0[BUF], bR1[BUF], bh, bl);                                   \
    bf16x8 ah, al;                                                           \
    if (GATHER) splitpack(gR0[BUF][0], gR0[BUF][1], ah, al);                 \
    else { ah = sh0[BUF]; al = sl0[BUF]; }                                   \
    acc[0] = MFMA_(ah, bh, acc[0]);                                          \
    acc[0] = MFMA_(ah, bl, acc[0]);                                          \
    acc[0] = MFMA_(al, bh, acc[0]);                                          \
    if (GATHER) splitpack(gR1[BUF][0], gR1[BUF][1], ah, al);                 \
    else { ah = sh1[BUF]; al = sl1[BUF]; }                                   \
    acc[1] = MFMA_(ah, bh, acc[1]);                                          \
    acc[1] = MFMA_(ah, bl, acc[1]);                                          \
    acc[1] = MFMA_(al, bh, acc[1]);                                          \
    if (GATHER) splitpack(gR2[BUF][0], gR2[BUF][1], ah, al);                 \
    else { ah = sh2[BUF]; al = sl2[BUF]; }                                   \
    acc[2] = MFMA_(ah, bh, acc[2]);                                          \
    acc[2] = MFMA_(ah, bl, acc[2]);                                          \
    acc[2] = MFMA_(al, bh, acc[2]);                                          \
    if (GATHER) splitpack(gR3[BUF][0], gR3[BUF][1], ah, al);                 \
    else { ah = sh3[BUF]; al = sl3[BUF]; }                                   \
    acc[3] = MFMA_(ah, bh, acc[3]);                                          \
    acc[3] = MFMA_(ah, bl, acc[3]);                                          \
    acc[3] = MFMA_(al, bh, acc[3]);                                          \
  }

  int ks = w;
  LOADFS(0, ks); ks += 8;
  int rem = nFS;              // nFS is even (4, 16)
  while (rem >= 2) {
    LOADFS(1, ks); ks += 8;
    COMPFS(0);
    if (rem > 2) { LOADFS(0, ks); ks += 8; }
    COMPFS(1);
    rem -= 2;
  }
#undef LOADFS
#undef COMPFS
}

// ---------------------------------------------------------------------------
// Fused dual-GEMM + epilogue. Tile: M=128 (all batch) x N=32. Grid 1-D over
// 32-col blocks. 8 waves K-split -> two-stage 64KB LDS reduce (XOR swizzle).
//   EPI=1: LSTM gates (bias add, sigmoid/tanh, c RMW, h -> pre-split staged)
//          block jb owns hidden units jb*8..jb*8+7; cols = gate*8 + unit.
//   EPI=0: bias add + f32 store (logits).
// ---------------------------------------------------------------------------
template<int EPI, int GATHER1>
__global__ __launch_bounds__(512, 2) void gemm_ks(
    const float* __restrict__ a1F,
    const uint16_t* __restrict__ a1Hi, const uint16_t* __restrict__ a1Lo,
    const int* __restrict__ ridx, int rstride,
    const float* __restrict__ W1, int K1,
    const uint16_t* __restrict__ a2Hi, const uint16_t* __restrict__ a2Lo,
    const float* __restrict__ W2, int K2,
    const float* __restrict__ bih, const float* __restrict__ bhh,
    float* __restrict__ cState,
    uint16_t* __restrict__ hOutHi, uint16_t* __restrict__ hOutLo,
    const float* __restrict__ bias, float* __restrict__ Cout)
{
  __shared__ float red[4][128 * 32];   // exactly 64 KiB

  const int jb   = blockIdx.x;
  const int tid  = threadIdx.x;
  const int w    = tid >> 6;     // 0..7
  const int lane = tid & 63;
  const int lrow = lane & 31;
  const int lgrp = lane >> 5;

  f32x16 acc[4];
#pragma unroll
  for (int mf = 0; mf < 4; ++mf)
#pragma unroll
    for (int r = 0; r < 16; ++r) acc[mf][r] = 0.0f;

  run_phase<GATHER1 != 0>(acc, a1F, a1Hi, a1Lo, ridx, rstride,
                          W1, K1, EPI == 1, jb, w, lrow, lgrp);
  if (K2 > 0)
    run_phase<false>(acc, nullptr, a2Hi, a2Lo, nullptr, 0,
                     W2, K2, EPI == 1, jb, w, lrow, lgrp);

  // two-stage partials -> LDS (conflict-free via col XOR row swizzle)
  const int wl = w & 3;
  if (w < 4) {
#pragma unroll
    for (int mf = 0; mf < 4; ++mf)
#pragma unroll
      for (int r = 0; r < 16; ++r) {
        const int row = mf * 32 + (r & 3) + 8 * (r >> 2) + 4 * lgrp;
        red[wl][row * 32 + (lrow ^ (row & 31))] = acc[mf][r];
      }
  }
  __syncthreads();
  if (w >= 4) {
#pragma unroll
    for (int mf = 0; mf < 4; ++mf)
#pragma unroll
      for (int r = 0; r < 16; ++r) {
        const int row = mf * 32 + (r & 3) + 8 * (r >> 2) + 4 * lgrp;
        red[wl][row * 32 + (lrow ^ (row & 31))] += acc[mf][r];
      }
  }
  __syncthreads();

  if constexpr (EPI == 1) {
    const int b  = tid & 127;
    const int uh = (tid >> 7) * 2;   // 0,2,4,6
#pragma unroll
    for (int q = 0; q < 2; ++q) {
      const int u = uh + q;
      float gs[4];
#pragma unroll
      for (int g = 0; g < 4; ++g) {
        const int cs = (g * 8 + u) ^ (b & 31);
        gs[g] = ((red[0][b * 32 + cs] + red[1][b * 32 + cs])
                 + red[2][b * 32 + cs]) + red[3][b * 32 + cs];
      }
      const int n = jb * 8 + u;
      float gi = gs[0] + bih[n]          + bhh[n];
      float gf = gs[1] + bih[H_ + n]     + bhh[H_ + n];
      float gg = gs[2] + bih[2 * H_ + n] + bhh[2 * H_ + n];
      float go = gs[3] + bih[3 * H_ + n] + bhh[3 * H_ + n];
      float si = 1.f / (1.f + expf(-gi));
      float sf = 1.f / (1.f + expf(-gf));
      float so = 1.f / (1.f + expf(-go));
      const size_t ci = (size_t)b * H_ + n;
      float cv = sf * cState[ci] + si * tanhf(gg);
      cState[ci] = cv;
      float hv = so * tanhf(cv);
      uint16_t hh, hl;
      split2(hv, hh, hl);
      const size_t hoff = (size_t)((n >> 4) * 4 + (b >> 5)) * 512
                        + (size_t)((n >> 3) & 1) * 256
                        + (size_t)(b & 31) * 8 + (size_t)(n & 7);
      hOutHi[hoff] = hh;
      hOutLo[hoff] = hl;
    }
  } else {
    const int b  = tid & 127;
    const int ch = (tid >> 7) * 8;
#pragma unroll
    for (int q = 0; q < 8; ++q) {
      const int col = ch + q;
      const int cs = col ^ (b & 31);
      float v = ((red[0][b * 32 + cs] + red[1][b * 32 + cs])
                 + red[2][b * 32 + cs]) + red[3][b * 32 + cs];
      Cout[(size_t)b * V_ + jb * 32 + col] = v + bias[jb * 32 + col];
    }
  }
}

// ---------------------------------------------------------------------------
// categorical sampling (verbatim from passing rounds 3/4/6)
// ---------------------------------------------------------------------------
__global__ __launch_bounds__(256) void sample_kernel(
    const float* __restrict__ logits, const uint32_t* __restrict__ keys,
    int t, int* __restrict__ out, int col)
{
  const int b = blockIdx.x;
  const int tid = threadIdx.x;
  const uint32_t k0 = keys[2 * t];
  const uint32_t k1 = keys[2 * t + 1];
  const float* lrow = logits + (size_t)b * V_;

  float best = -3.4e38f;
  int bestIdx = 0;
  for (int v = tid; v < V_; v += 256) {
    uint32_t j = (uint32_t)(b * V_ + v);
    uint32_t o0, o1;
    threefry2x32(k0, k1, 0u, j, o0, o1);
    uint32_t bits = o0 ^ o1;
    float f = __uint_as_float((bits >> 9) | 0x3f800000u) - 1.0f;
    float u = fmaxf(1.17549435e-38f, f + 1.17549435e-38f);
    float t1 = (float)log((double)u);
    float t2 = -t1;
    float t3 = (float)log((double)t2);
    float val = (-t3) + lrow[v];
    if (val > best) { best = val; bestIdx = v; }
  }

  __shared__ float sv[256];
  __shared__ int   si[256];
  sv[tid] = best; si[tid] = bestIdx;
  __syncthreads();
  for (int s = 128; s > 0; s >>= 1) {
    if (tid < s) {
      float v2 = sv[tid + s]; int i2 = si[tid + s];
      if (v2 > sv[tid] || (v2 == sv[tid] && i2 < si[tid])) { sv[tid] = v2; si[tid] = i2; }
    }
    __syncthreads();
  }
  if (tid == 0) out[b * S_ + col] = si[0];
}

// ---------------------------------------------------------------------------
extern "C" void kernel_launch(void* const* d_in, const int* in_sizes, int n_in,
                              void* d_out, int out_size, void* d_ws, size_t ws_size,
                              hipStream_t stream) {
  const int*   x    = (const int*)  d_in[0];
  const float* emb  = (const float*)d_in[3];
  const float* Wih0 = (const float*)d_in[4];
  const float* Whh0 = (const float*)d_in[5];
  const float* bih0 = (const float*)d_in[6];
  const float* bhh0 = (const float*)d_in[7];
  const float* Wih1 = (const float*)d_in[8];
  const float* Whh1 = (const float*)d_in[9];
  const float* bih1 = (const float*)d_in[10];
  const float* bhh1 = (const float*)d_in[11];
  const float* Wlin = (const float*)d_in[12];
  const float* blin = (const float*)d_in[13];
  int* out = (int*)d_out;

  // ---- workspace carve-up (~9.9 MB total) ----
  char* wp = (char*)d_ws;
  size_t o = 0;
  auto alloc = [&](size_t bytes) {
    void* p = wp + o; o += (bytes + 255) & ~(size_t)255; return p;
  };
  float*    logits = (float*)   alloc((size_t)B_ * V_ * 4);
  uint32_t* keys   = (uint32_t*)alloc(512);
  float*    c0     = (float*)   alloc((size_t)B_ * H_ * 4);   // zero-block start
  float*    c1     = (float*)   alloc((size_t)B_ * H_ * 4);
  uint16_t* hS0hi[2]; uint16_t* hS0lo[2]; uint16_t* hS1hi[2]; uint16_t* hS1lo[2];
  for (int i = 0; i < 2; ++i) hS0hi[i] = (uint16_t*)alloc((size_t)B_ * H_ * 2);
  for (int i = 0; i < 2; ++i) hS0lo[i] = (uint16_t*)alloc((size_t)B_ * H_ * 2);
  for (int i = 0; i < 2; ++i) hS1hi[i] = (uint16_t*)alloc((size_t)B_ * H_ * 2);
  for (int i = 0; i < 2; ++i) hS1lo[i] = (uint16_t*)alloc((size_t)B_ * H_ * 2);
  size_t zeroBytes = (size_t)((char*)hS1lo[1] + (size_t)B_ * H_ * 2 - (char*)c0);

  hipMemsetAsync(c0, 0, zeroBytes, stream);
  keys_kernel<<<1, 64, 0, stream>>>(keys);
  copy_prefix<<<(B_ * GIVEN_) / 256, 256, 0, stream>>>(x, out);

  int p = 0;
  auto lstm_step = [&](const int* ridx) {
    // layer 0: [emb-gather] @ Wih0^T + h0 @ Whh0^T -> gates -> h0', c0
    gemm_ks<1, 1><<<H_ / 8, 512, 0, stream>>>(
        emb, nullptr, nullptr, ridx, S_, Wih0, E_,
        hS0hi[p], hS0lo[p], Whh0, H_,
        bih0, bhh0, c0, hS0hi[p ^ 1], hS0lo[p ^ 1], nullptr, nullptr);
    // layer 1: h0' @ Wih1^T + h1 @ Whh1^T -> gates -> h1', c1
    gemm_ks<1, 0><<<H_ / 8, 512, 0, stream>>>(
        nullptr, hS0hi[p ^ 1], hS0lo[p ^ 1], nullptr, 0, Wih1, H_,
        hS1hi[p], hS1lo[p], Whh1, H_,
        bih1, bhh1, c1, hS1hi[p ^ 1], hS1lo[p ^ 1], nullptr, nullptr);
    p ^= 1;
  };

  // teacher forcing
  for (int t = 0; t < GIVEN_; ++t) {
    lstm_step(x + t);
  }

  // rollout
  for (int t = 0; t < S_ - GIVEN_; ++t) {
    const int* ridx = (t == 0) ? (x + (GIVEN_ - 1)) : (out + (GIVEN_ + t - 1));
    lstm_step(ridx);
    gemm_ks<0, 0><<<V_ / 32, 512, 0, stream>>>(
        nullptr, hS1hi[p], hS1lo[p], nullptr, 0, Wlin, H_,
        nullptr, nullptr, nullptr, 0,
        nullptr, nullptr, nullptr, nullptr, nullptr, blin, logits);
    sample_kernel<<<B_, 256, 0, stream>>>(logits, keys, t, out, GIVEN_ + t);
  }
}